// Round 4
// baseline (166.116 us; speedup 1.0000x reference)
//
#include <hip/hip_runtime.h>
#include <stdint.h>

typedef unsigned short u16;
typedef unsigned int   u32;
typedef unsigned char  u8;
typedef signed char    s8;

#define B_    128
#define S_    1024
#define H_    1024
#define E_    256
#define EMB_  100
#define EMBP_ 128
#define V_    50000
#define NTOK_ (B_*S_)
#define FSINF 0x7F7F7F7F

typedef __attribute__((ext_vector_type(8))) short bf16x8;
typedef __attribute__((ext_vector_type(4))) float f32x4;
typedef __attribute__((ext_vector_type(4))) int   i32x4;

__device__ __forceinline__ u16 f2bf(float f){ u32 x=__float_as_uint(f); return (u16)((x + 0x7FFFu + ((x>>16)&1u))>>16); }
__device__ __forceinline__ float quantw(float w){ float r = rintf(w*16.f)*0.0625f; return fminf(fmaxf(r,-0.9375f),0.9375f); }

__device__ __forceinline__ void gll16(const void* g, void* l){
  __builtin_amdgcn_global_load_lds((const __attribute__((address_space(1))) void*)g,
                                   (__attribute__((address_space(3))) void*)l, 16, 0, 0);
}

// ---------------- merged prep ----------------

__global__ __launch_bounds__(256) void prep_all_k(const float* __restrict__ emb,
    const float* __restrict__ W1, const float* __restrict__ W2,
    const float* __restrict__ b2, const float* __restrict__ br2,
    u16* __restrict__ embhi, u16* __restrict__ w1hi, s8* __restrict__ qW2i,
    float* __restrict__ b2br2)
{
  int j = blockIdx.x*256 + threadIdx.x;
  const int N0 = V_*EMBP_;
  const int N1 = E_*EMBP_;
  const int N2 = H_*E_;
  const int N3 = H_;
  if (j < N0){
    int v = j >> 7, k = j & 127;
    embhi[j] = f2bf((k < EMB_) ? emb[v*EMB_ + k] : 0.f);
  } else if ((j -= N0) < N1){
    int n = j >> 7, k = j & 127;
    w1hi[j] = f2bf((k < EMB_) ? W1[n*EMB_ + k] : 0.f);
  } else if ((j -= N1) < N2){
    float q = rintf(W2[j]*16.f);
    qW2i[j] = (s8)(int)fminf(fmaxf(q, -15.f), 15.f);
  } else if ((j -= N2) < N3){
    b2br2[j] = b2[j] + br2[j];
  }
}

// ---------------- GEMM1: xq = quant(relu(gather(emb) @ W1^T + b1)) as int8 (x16) ----------------
// 128x128 tiles, K=128. k-step0 staged via global_load_lds; k-step1 prefetched to REGISTERS
// at t=0 (one latency exposure total), ds_written after step0 compute (T14).

__device__ __forceinline__ void g1_step(const char* As, const char* Bs, f32x4 (&acc)[4][4],
                                        int wm, int wn, int l)
{
  bf16x8 af[2][4], bfv[2][4];
  #pragma unroll
  for (int kk = 0; kk < 2; ++kk){
    #pragma unroll
    for (int mi = 0; mi < 4; ++mi){
      int rA = wm*64 + mi*16 + (l & 15);
      af[kk][mi] = *(const bf16x8*)&As[rA*128 + (((kk*4 + (l >> 4)) ^ (rA & 7)) * 16)];
    }
    #pragma unroll
    for (int ni = 0; ni < 4; ++ni){
      int rB = wn*64 + ni*16 + (l & 15);
      bfv[kk][ni] = *(const bf16x8*)&Bs[rB*128 + (((kk*4 + (l >> 4)) ^ (rB & 7)) * 16)];
    }
  }
  __builtin_amdgcn_s_setprio(1);
  #pragma unroll
  for (int kk = 0; kk < 2; ++kk)
    #pragma unroll
    for (int mi = 0; mi < 4; ++mi)
      #pragma unroll
      for (int ni = 0; ni < 4; ++ni)
        acc[mi][ni] = __builtin_amdgcn_mfma_f32_16x16x32_bf16(af[kk][mi], bfv[kk][ni], acc[mi][ni], 0, 0, 0);
  __builtin_amdgcn_s_setprio(0);
}

__global__ __launch_bounds__(256) void gemm1_k(const int* __restrict__ inputs,
    const u16* __restrict__ embhi, const u16* __restrict__ w1hi,
    const float* __restrict__ b1, u8* __restrict__ xq)
{
  __shared__ __align__(16) char As[16384];
  __shared__ __align__(16) char Bs[16384];
  const int tid = threadIdx.x;
  const int bx = blockIdx.x;
  const int n0 = ((bx >> 3) & 1) * 128;
  const int m0 = (((bx & 7) << 7) + (bx >> 4)) * 128;
  const int l = tid & 63, wid = tid >> 6;
  const int wm = wid >> 1, wn = wid & 1;

  f32x4 acc[4][4];
  #pragma unroll
  for (int a = 0; a < 4; ++a)
    #pragma unroll
    for (int c = 0; c < 4; ++c)
      acc[a][c] = (f32x4)0.f;

  // stage k-step0 (async -> LDS) and issue k-step1 loads to registers now
  int ga4[4];
  #pragma unroll
  for (int i = 0; i < 4; ++i){
    int p = tid + i*256, r = p >> 3, c = p & 7;
    ga4[i] = inputs[m0 + r];
    int sw = (c ^ (r & 7)) * 16;
    gll16((const char*)embhi + (size_t)ga4[i]*256 + sw, As + p*16);
    gll16((const char*)w1hi + (size_t)(n0 + r)*256 + sw, Bs + p*16);
  }
  i32x4 pfA[4], pfB[4];
  #pragma unroll
  for (int q = 0; q < 4; ++q){
    int p = tid + q*256, r = p >> 3, c = p & 7;
    int sw = 128 + ((c ^ (r & 7)) * 16);
    pfA[q] = *(const i32x4*)((const char*)embhi + (size_t)ga4[q]*256 + sw);
    pfB[q] = *(const i32x4*)((const char*)w1hi + (size_t)(n0 + r)*256 + sw);
  }
  __syncthreads();

  g1_step(As, Bs, acc, wm, wn, l);
  __syncthreads();                      // frag reads done -> safe to overwrite

  #pragma unroll
  for (int q = 0; q < 4; ++q){
    int p = tid + q*256;
    *(i32x4*)(As + p*16) = pfA[q];      // compiler inserts vmcnt wait on pf regs
    *(i32x4*)(Bs + p*16) = pfB[q];
  }
  __syncthreads();

  g1_step(As, Bs, acc, wm, wn, l);

  #pragma unroll
  for (int mi = 0; mi < 4; ++mi){
    #pragma unroll
    for (int ni = 0; ni < 4; ++ni){
      int col = n0 + wn*64 + ni*16 + (l & 15);
      float bv = b1[col];
      #pragma unroll
      for (int j = 0; j < 4; ++j){
        int row = m0 + wm*64 + mi*16 + ((l >> 4)*4) + j;
        float v = fmaxf(acc[mi][ni][j] + bv, 0.f);
        int q = (int)rintf(v*16.f);
        q = (q > 15) ? 15 : q;
        xq[(size_t)row*E_ + col] = (u8)q;
      }
    }
  }
}

// ---------------- fused GEMM2 + parallel membrane scan ----------------
// block = (batch b, 128-h slice). B resident in VGPRs; A single 16KB buffer with
// in-loop async prefetch; Sc bf16 (cvt_pk); LDS 33KB -> 4 blocks/CU, single round.

__global__ __launch_bounds__(256, 4) void gemm2_k(const s8* __restrict__ xq,
    const s8* __restrict__ qW2i, const float* __restrict__ b2br2, int* __restrict__ firstspike)
{
  __shared__ __align__(16) char LB[33792];  // [0,16K): A (B staged over [0,32K) at init)
                                            // [16K,32K): Sc bf16 [128h][64t] swizzled
                                            // [32K,+1K): carry[2][128] f32
  float* carry = (float*)(LB + 32768);

  const int tid = threadIdx.x;
  const int bx  = blockIdx.x;
  const int xcd = bx & 7, idx = bx >> 3;
  const int b   = xcd*16 + (idx >> 3);       // all 8 h-slices of a batch on one XCD
  const int n0  = (idx & 7) * 128;
  const int l = tid & 63, wid = tid >> 6;
  const int wm = wid >> 1, wn = wid & 1;
  const int l4 = l >> 4;

  // stage B slice (128h x 256k i8, pre-inverse-swizzled) across [0,32K)
  #pragma unroll
  for (int i = 0; i < 8; ++i){
    int p = tid + i*256, r = p >> 4, g = p & 15;
    gll16(qW2i + (size_t)(n0 + r)*256 + ((g ^ (r & 7))*16), LB + p*16);
  }
  __syncthreads();

  i32x4 bq[4][4];
  #pragma unroll
  for (int ni = 0; ni < 4; ++ni){
    int rB = wn*64 + ni*16 + (l & 15);
    #pragma unroll
    for (int ks = 0; ks < 4; ++ks)
      bq[ni][ks] = *(const i32x4*)&LB[rB*256 + (((ks*4 + l4) ^ (rB & 7))*16)];
  }
  float bias_e[4];
  #pragma unroll
  for (int ni = 0; ni < 4; ++ni)
    bias_e[ni] = b2br2[n0 + wn*64 + ni*16 + (l & 15)];
  if (tid < 128) carry[tid] = 0.f;
  __syncthreads();                           // B consumed -> region reusable as A

  // stage A(0)
  const s8* Ab0 = xq + (size_t)b*S_*E_;
  #pragma unroll
  for (int i = 0; i < 4; ++i){
    int p = tid + i*256, r = p >> 4, g = p & 15;
    gll16(Ab0 + (size_t)r*256 + ((g ^ (r & 7))*16), LB + p*16);
  }
  __syncthreads();

  const int hsc = tid & 127, chunk = tid >> 7;
  const int hx7 = hsc & 7;
  const int rA0 = wm*32 + (l & 15), rA1 = rA0 + 16;
  float mmax = -1e30f;

  for (int s = 0; s < 16; ++s){
    i32x4 acc[2][4];
    #pragma unroll
    for (int mi = 0; mi < 2; ++mi)
      #pragma unroll
      for (int ni = 0; ni < 4; ++ni)
        acc[mi][ni] = (i32x4)0;

    __builtin_amdgcn_s_setprio(1);
    #pragma unroll
    for (int ks = 0; ks < 4; ++ks){
      i32x4 a0 = *(const i32x4*)&LB[rA0*256 + (((ks*4 + l4) ^ (rA0 & 7))*16)];
      i32x4 a1 = *(const i32x4*)&LB[rA1*256 + (((ks*4 + l4) ^ (rA1 & 7))*16)];
      #pragma unroll
      for (int ni = 0; ni < 4; ++ni){
        acc[0][ni] = __builtin_amdgcn_mfma_i32_16x16x64_i8(a0, bq[ni][ks], acc[0][ni], 0, 0, 0);
        acc[1][ni] = __builtin_amdgcn_mfma_i32_16x16x64_i8(a1, bq[ni][ks], acc[1][ni], 0, 0, 0);
      }
    }
    __builtin_amdgcn_s_setprio(0);

    // epilogue: I = acc/256 + bias -> Sc bf16 [h][t], granule swizzle, b64 stores
    #pragma unroll
    for (int mi = 0; mi < 2; ++mi){
      int tg = wm*4 + mi*2 + (l4 >> 1);
      int s8off = (l4 & 1)*8;
      #pragma unroll
      for (int ni = 0; ni < 4; ++ni){
        int h = wn*64 + ni*16 + (l & 15);
        float v0 = fmaf((float)acc[mi][ni][0], 0.00390625f, bias_e[ni]);
        float v1 = fmaf((float)acc[mi][ni][1], 0.00390625f, bias_e[ni]);
        float v2 = fmaf((float)acc[mi][ni][2], 0.00390625f, bias_e[ni]);
        float v3 = fmaf((float)acc[mi][ni][3], 0.00390625f, bias_e[ni]);
        u32 w0, w1;
        asm("v_cvt_pk_bf16_f32 %0, %1, %2" : "=v"(w0) : "v"(v0), "v"(v1));
        asm("v_cvt_pk_bf16_f32 %0, %1, %2" : "=v"(w1) : "v"(v2), "v"(v3));
        uint2 wv; wv.x = w0; wv.y = w1;
        *(uint2*)&LB[16384 + h*128 + ((tg ^ (h & 7))*16) + s8off] = wv;
      }
    }
    __syncthreads();   // B1: Sc ready; all A(s) frag reads done

    // async prefetch A(s+1) into the (now-free) A buffer; lands by B2's drain
    if (s < 15){
      const s8* Ab = Ab0 + (size_t)(s + 1)*64*256;
      #pragma unroll
      for (int i = 0; i < 4; ++i){
        int p = tid + i*256, r = p >> 4, g = p & 15;
        gll16(Ab + (size_t)r*256 + ((g ^ (r & 7))*16), LB + p*16);
      }
    }

    // scan: chunk0 = t[0..31] exact from carry; chunk1 = warm t[16..31], live t[32..63]
    const char* sb = LB + 16384 + hsc*128;
    if (chunk == 0){
      float m = carry[(s & 1)*128 + hsc];
      #pragma unroll
      for (int tg = 0; tg < 4; ++tg){
        uint4 w = *(const uint4*)(sb + ((tg ^ hx7)*16));
        const u32* wp = (const u32*)&w;
        #pragma unroll
        for (int j = 0; j < 4; ++j){
          m = fmaf(m, 0.2f, __uint_as_float(wp[j] << 16));
          float m2 = fmaf(m, 0.2f, __uint_as_float(wp[j] & 0xFFFF0000u));
          mmax = fmaxf(fmaxf(mmax, m), m2);
          m = m2;
        }
      }
    } else {
      float m = 0.f;
      #pragma unroll
      for (int tg = 2; tg < 4; ++tg){
        uint4 w = *(const uint4*)(sb + ((tg ^ hx7)*16));
        const u32* wp = (const u32*)&w;
        #pragma unroll
        for (int j = 0; j < 4; ++j){
          m = fmaf(m, 0.2f, __uint_as_float(wp[j] << 16));
          m = fmaf(m, 0.2f, __uint_as_float(wp[j] & 0xFFFF0000u));
        }
      }
      #pragma unroll
      for (int tg = 4; tg < 8; ++tg){
        uint4 w = *(const uint4*)(sb + ((tg ^ hx7)*16));
        const u32* wp = (const u32*)&w;
        #pragma unroll
        for (int j = 0; j < 4; ++j){
          m = fmaf(m, 0.2f, __uint_as_float(wp[j] << 16));
          float m2 = fmaf(m, 0.2f, __uint_as_float(wp[j] & 0xFFFF0000u));
          mmax = fmaxf(fmaxf(mmax, m), m2);
          m = m2;
        }
      }
      carry[((s + 1) & 1)*128 + hsc] = m;
    }
    __syncthreads();   // B2: scan done; A(s+1) landed (vmcnt drained by barrier)
  }
  if (mmax > 0.5f) atomicMin(&firstspike[b], 0);
}

// ---------------- exact fallback (spiking batches only; quantizes Wr2 on the fly) ----------------

__global__ __launch_bounds__(256) void fallback_k(const s8* __restrict__ xq, const s8* __restrict__ qW2i,
    const float* __restrict__ b2br2, const float* __restrict__ Wr2,
    const int* __restrict__ firstspike, float* __restrict__ sumspike)
{
  const int b = blockIdx.x;
  if (firstspike[b] >= S_) return;
  const int tid = threadIdx.x;
  __shared__ int slist[H_];
  __shared__ int scount;
  __shared__ s8 xrow[E_];
  float mem[4] = {0,0,0,0}, sp[4] = {0,0,0,0}, ss[4] = {0,0,0,0};

  for (int t = 0; t < S_; ++t){
    if (tid == 0) scount = 0;
    __syncthreads();
    #pragma unroll
    for (int j = 0; j < 4; ++j)
      if (sp[j] > 0.5f){ int k = atomicAdd(&scount, 1); slist[k] = tid + j*256; }
    if (tid < 64) ((int*)xrow)[tid] = ((const int*)(xq + (size_t)(b*S_ + t)*E_))[tid];
    __syncthreads();
    int sc = scount;
    #pragma unroll
    for (int j = 0; j < 4; ++j){
      int h = tid + j*256;
      const s8* wr = qW2i + (size_t)h*E_;
      int ia = 0;
      #pragma unroll 4
      for (int k = 0; k < E_; k += 4){
        ia += (int)xrow[k]*(int)wr[k] + (int)xrow[k+1]*(int)wr[k+1]
            + (int)xrow[k+2]*(int)wr[k+2] + (int)xrow[k+3]*(int)wr[k+3];
      }
      float Iv = (float)ia*(1.f/256.f) + b2br2[h];
      float rec = 0.f;
      for (int u = 0; u < sc; ++u) rec += quantw(Wr2[(size_t)h*H_ + slist[u]]);
      mem[j] = mem[j]*0.2f*(1.f - sp[j]) + Iv + rec;
    }
    #pragma unroll
    for (int j = 0; j < 4; ++j){ float ns = (mem[j] > 0.5f) ? 1.f : 0.f; sp[j] = ns; ss[j] += ns; }
    __syncthreads();
  }
  #pragma unroll
  for (int j = 0; j < 4; ++j)
    sumspike[((size_t)b << 10) + tid + j*256] = ss[j];
}

// ---------------- final tiny GEMM ----------------

__global__ __launch_bounds__(256) void final_k(const float* __restrict__ ss, const float* __restrict__ W3,
    const float* __restrict__ b3, float* __restrict__ out)
{
  int b = blockIdx.x, tid = threadIdx.x;
  float p0 = 0.f, p1 = 0.f;
  for (int h = tid; h < H_; h += 256){
    float s = ss[((size_t)b << 10) + h];
    p0 += s*W3[h]; p1 += s*W3[H_ + h];
  }
  #pragma unroll
  for (int o = 32; o > 0; o >>= 1){ p0 += __shfl_down(p0, o, 64); p1 += __shfl_down(p1, o, 64); }
  __shared__ float r0[4], r1[4];
  if ((tid & 63) == 0){ r0[tid >> 6] = p0; r1[tid >> 6] = p1; }
  __syncthreads();
  if (tid == 0){
    out[b*2 + 0] = r0[0] + r0[1] + r0[2] + r0[3] + b3[0];
    out[b*2 + 1] = r1[0] + r1[1] + r1[2] + r1[3] + b3[1];
  }
}

// ---------------- host ----------------

extern "C" void kernel_launch(void* const* d_in, const int* in_sizes, int n_in,
                              void* d_out, int out_size, void* d_ws, size_t ws_size,
                              hipStream_t stream)
{
  (void)in_sizes; (void)n_in; (void)out_size; (void)ws_size;
  const int*   inputs = (const int*)  d_in[0];
  const float* emb    = (const float*)d_in[1];
  const float* W1     = (const float*)d_in[2];
  const float* b1     = (const float*)d_in[3];
  const float* W2     = (const float*)d_in[4];
  const float* b2     = (const float*)d_in[5];
  const float* Wr2    = (const float*)d_in[6];
  const float* br2    = (const float*)d_in[7];
  const float* W3     = (const float*)d_in[8];
  const float* b3     = (const float*)d_in[9];
  float* out = (float*)d_out;
  char* ws = (char*)d_ws;

  size_t off = 0;
  auto alloc = [&](size_t bytes)->char*{
    char* p = ws + off; off = (off + bytes + 255) & ~(size_t)255; return p;
  };
  u16*   embhi    = (u16*)  alloc((size_t)V_*EMBP_*2);   // 12.8 MB
  u16*   w1hi     = (u16*)  alloc((size_t)E_*EMBP_*2);
  s8*    qW2i     = (s8*)   alloc((size_t)H_*E_);
  float* b2br2    = (float*)alloc((size_t)H_*4);
  u8*    xq       = (u8*)   alloc((size_t)NTOK_*E_);     // 32 MB
  float* sumspike = (float*)alloc((size_t)B_*H_*4);
  int*   firstspk = (int*)  alloc((size_t)B_*4);

  hipMemsetAsync(sumspike, 0,    (size_t)B_*H_*4, stream);
  hipMemsetAsync(firstspk, 0x7F, (size_t)B_*4,    stream);

  {
    const int total = V_*EMBP_ + E_*EMBP_ + H_*E_ + H_;
    prep_all_k<<<(total + 255)/256, 256, 0, stream>>>(emb, W1, W2, b2, br2,
                                                      embhi, w1hi, qW2i, b2br2);
  }
  gemm1_k<<<2048, 256, 0, stream>>>(inputs, embhi, w1hi, b1, xq);
  gemm2_k<<<1024, 256, 0, stream>>>((const s8*)xq, qW2i, b2br2, firstspk);
  fallback_k<<<B_, 256, 0, stream>>>((const s8*)xq, qW2i, b2br2, Wr2, firstspk, sumspike);
  final_k<<<B_, 256, 0, stream>>>(sumspike, W3, b3, out);
}